// Round 6
// baseline (433.013 us; speedup 1.0000x reference)
//
#include <hip/hip_runtime.h>
#include <stdint.h>

typedef unsigned long long u64;
typedef unsigned int u32;

// ---------------------------------------------------------------------------
// Constants: 17 feats/row, beta = col 9, cc = cols 14..16, T_B=0.85, T_D^2=0.09.
// Greedy condensation == scan candidates in descending (betaBits, ~idx) key
// order, accept iff not within T_D of any previously accepted center.
// R6: scan de-serialized (no compaction/ballot; per-thread alive bitmask +
// prefetch + register top-8) and pop cut to one barrier/iter (parity LDS).
// R5's scan kept ~1 load in flight per wave (ballot+atomic after each load)
// -> 225us at 7GB/s; this removes the dependence.
// ---------------------------------------------------------------------------

__global__ void init_kernel(int* segCount, int* condCount, int nseg) {
    int t = threadIdx.x;
    if (t < nseg) { segCount[t] = 0; condCount[t] = 0; }
}

// Single-pass filter: block-local LDS staging, ONE global atomic per block.
__launch_bounds__(256)
__global__ void filter_kernel(const float* __restrict__ x, int S, int chunk, int bps,
                              int* __restrict__ segCount,
                              float4* __restrict__ A, int* __restrict__ iA, int CAP) {
    __shared__ float4 stg[1024];
    __shared__ int sgi[1024];
    __shared__ int s_cnt, s_base;
    int b = blockIdx.x;
    int s = b / bps, c = b % bps;
    int start = s * S + c * chunk;
    int end = min(start + chunk, s * S + S);
    if (threadIdx.x == 0) s_cnt = 0;
    __syncthreads();
    for (int i = start + threadIdx.x; i < end; i += 256) {
        float beta = x[(size_t)i * 17 + 9];
        if (beta >= 0.85f) {
            int p = atomicAdd(&s_cnt, 1);
            if (p < 1024) {
                stg[p] = make_float4(x[(size_t)i * 17 + 14], x[(size_t)i * 17 + 15],
                                     x[(size_t)i * 17 + 16], beta);
                sgi[p] = i;
            }
        }
    }
    __syncthreads();
    if (threadIdx.x == 0) s_base = atomicAdd(&segCount[s], min(s_cnt, 1024));
    __syncthreads();
    int cnt = min(s_cnt, 1024);
    for (int k = threadIdx.x; k < cnt; k += 256) {
        int pos = s_base + k;
        if (pos < CAP) {
            A[(size_t)s * CAP + pos] = stg[k];
            iA[(size_t)s * CAP + pos] = sgi[k];
        }
    }
}

#define DSQ(ax,ay,az,bx,by,bz) \
    __fadd_rn(__fadd_rn(__fmul_rn(__fsub_rn(ax,bx),__fsub_rn(ax,bx)), \
                        __fmul_rn(__fsub_rn(ay,by),__fsub_rn(ay,by))), \
              __fmul_rn(__fsub_rn(az,bz),__fsub_rn(az,bz)))

// One block (1024 thr) per segment.
__launch_bounds__(1024)
__global__ void greedy_kernel(const float4* __restrict__ A, const int* __restrict__ iA,
                              const int* __restrict__ candCount, int CAP,
                              int* __restrict__ condList, int* __restrict__ condCount,
                              int CCAP) {
    const int s = blockIdx.x;
    const int tid = threadIdx.x;
    const int lane = tid & 63;
    const int wid = tid >> 6;

    __shared__ u64 wkey[2][16];
    __shared__ float4 wctr[2][16];
    __shared__ float4 ctr[1024];
    __shared__ int ctrGi[1024];
    __shared__ u64 s_H;
    __shared__ int s_newN;

    const float4* cand = A + (size_t)s * CAP;
    const int* gia = iA + (size_t)s * CAP;
    int n = candCount[s]; if (n > CAP) n = CAP;

    // alive bit t <-> candidate j = tid + (t<<10)
    int nslots = (n > tid) ? ((n - tid + 1023) >> 10) : 0;
    u64 alive = (nslots >= 64) ? ~0ull : ((1ull << nslots) - 1ull);

    int condTotal = 0, scanned = 0, passes = 0, par = 0;

    while (true) {
        if (tid == 0) { s_H = 0; s_newN = 0; }
        __syncthreads();

        // ---- SCAN: prefetched loads, coverage vs new centers, top-8 insert ----
        u64 K0=0,K1=0,K2=0,K3=0,K4=0,K5=0,K6=0,K7=0,K8=0;
        float X0=0,Y0=0,Z0=0,X1=0,Y1=0,Z1=0,X2=0,Y2=0,Z2=0,X3=0,Y3=0,Z3=0,
              X4=0,Y4=0,Z4=0,X5=0,Y5=0,Z5=0,X6=0,Y6=0,Z6=0,X7=0,Y7=0,Z7=0;

        u64 rem = alive;
        int tA = -1; float4 cA = make_float4(0,0,0,0); int gA = 0;
        if (rem) { tA = __ffsll(rem) - 1; rem &= rem - 1;
                   int j = tid + (tA << 10); cA = cand[j]; gA = gia[j]; }
        while (tA >= 0) {
            int tB = -1; float4 cB = make_float4(0,0,0,0); int gB = 0;
            if (rem) { tB = __ffsll(rem) - 1; rem &= rem - 1;
                       int j = tid + (tB << 10); cB = cand[j]; gB = gia[j]; }
            // coverage vs centers committed since this candidate's last check
            bool live = true;
            for (int m = scanned; m < condTotal; ++m) {
                float4 q = ctr[m];   // uniform m -> LDS broadcast
                if (DSQ(cA.x, cA.y, cA.z, q.x, q.y, q.z) < 0.09f) { live = false; break; }
            }
            if (!live) {
                alive &= ~(1ull << tA);
            } else {
                u64 key = ((u64)__float_as_uint(cA.w) << 32) | (u64)(~(u32)gA);
                if (key > K8) {
                    if (key <= K7) K8 = key;
                    else { K8 = K7;
                    if (key <= K6) { K7=key; X7=cA.x; Y7=cA.y; Z7=cA.z; }
                    else { K7=K6; X7=X6; Y7=Y6; Z7=Z6;
                    if (key <= K5) { K6=key; X6=cA.x; Y6=cA.y; Z6=cA.z; }
                    else { K6=K5; X6=X5; Y6=Y5; Z6=Z5;
                    if (key <= K4) { K5=key; X5=cA.x; Y5=cA.y; Z5=cA.z; }
                    else { K5=K4; X5=X4; Y5=Y4; Z5=Z4;
                    if (key <= K3) { K4=key; X4=cA.x; Y4=cA.y; Z4=cA.z; }
                    else { K4=K3; X4=X3; Y4=Y3; Z4=Z3;
                    if (key <= K2) { K3=key; X3=cA.x; Y3=cA.y; Z3=cA.z; }
                    else { K3=K2; X3=X2; Y3=Y2; Z3=Z2;
                    if (key <= K1) { K2=key; X2=cA.x; Y2=cA.y; Z2=cA.z; }
                    else { K2=K1; X2=X1; Y2=Y1; Z2=Z1;
                    if (key <= K0) { K1=key; X1=cA.x; Y1=cA.y; Z1=cA.z; }
                    else { K1=K0; X1=X0; Y1=Y0; Z1=Z0;
                           K0=key; X0=cA.x; Y0=cA.y; Z0=cA.z; } } } } } } } }
                }
            }
            tA = tB; cA = cB; gA = gB;
        }

        // ---- newN + horizon ----
        int myAlive = __popcll(alive);
        u64 m9 = K8;
        for (int off = 32; off > 0; off >>= 1) {
            myAlive += __shfl_down(myAlive, off);
            u64 o = __shfl_down(m9, off);
            if (o > m9) m9 = o;
        }
        if (lane == 0) { atomicAdd(&s_newN, myAlive); atomicMax(&s_H, m9); }
        __syncthreads();
        if (s_newN == 0) break;
        u64 H = s_H;
        scanned = condTotal;

        // ---- POP: one barrier per committed pick ----
        while (condTotal < 1024) {
            // local argmax over 8 slots (static indexing only)
            u64 mk = K0; int ms = 0;
            if (K1 > mk) { mk = K1; ms = 1; }
            if (K2 > mk) { mk = K2; ms = 2; }
            if (K3 > mk) { mk = K3; ms = 3; }
            if (K4 > mk) { mk = K4; ms = 4; }
            if (K5 > mk) { mk = K5; ms = 5; }
            if (K6 > mk) { mk = K6; ms = 6; }
            if (K7 > mk) { mk = K7; ms = 7; }
            float bx, by, bz;
            if      (ms == 0) { bx=X0; by=Y0; bz=Z0; }
            else if (ms == 1) { bx=X1; by=Y1; bz=Z1; }
            else if (ms == 2) { bx=X2; by=Y2; bz=Z2; }
            else if (ms == 3) { bx=X3; by=Y3; bz=Z3; }
            else if (ms == 4) { bx=X4; by=Y4; bz=Z4; }
            else if (ms == 5) { bx=X5; by=Y5; bz=Z5; }
            else              { bx=X6; by=Y6; bz=Z6; }
            if (ms == 7)      { bx=X7; by=Y7; bz=Z7; }
            // wave butterfly carrying (key, src)
            int src = lane;
            for (int off = 32; off > 0; off >>= 1) {
                u64 ok = __shfl_xor(mk, off);
                int oi = __shfl_xor(src, off);
                if (ok > mk) { mk = ok; src = oi; }
            }
            if (lane == 0) wkey[par][wid] = mk;
            if (mk != 0 && lane == src) wctr[par][wid] = make_float4(bx, by, bz, 0.f);
            __syncthreads();
            // all threads redundantly reduce the 16 wave maxima
            u64 bk = 0; int bL = 0;
            #pragma unroll
            for (int w = 0; w < 16; ++w) {
                u64 kk = wkey[par][w];
                if (kk > bk) { bk = kk; bL = w; }
            }
            if (bk <= H) break;                  // uniform decision
            float4 cc = wctr[par][bL];           // uniform -> broadcast
            // kill own covered pending (winner kills itself at dist 0)
            if (K0 && DSQ(X0,Y0,Z0,cc.x,cc.y,cc.z) < 0.09f) K0 = 0;
            if (K1 && DSQ(X1,Y1,Z1,cc.x,cc.y,cc.z) < 0.09f) K1 = 0;
            if (K2 && DSQ(X2,Y2,Z2,cc.x,cc.y,cc.z) < 0.09f) K2 = 0;
            if (K3 && DSQ(X3,Y3,Z3,cc.x,cc.y,cc.z) < 0.09f) K3 = 0;
            if (K4 && DSQ(X4,Y4,Z4,cc.x,cc.y,cc.z) < 0.09f) K4 = 0;
            if (K5 && DSQ(X5,Y5,Z5,cc.x,cc.y,cc.z) < 0.09f) K5 = 0;
            if (K6 && DSQ(X6,Y6,Z6,cc.x,cc.y,cc.z) < 0.09f) K6 = 0;
            if (K7 && DSQ(X7,Y7,Z7,cc.x,cc.y,cc.z) < 0.09f) K7 = 0;
            if (tid == 0) {
                ctr[condTotal] = cc;
                ctrGi[condTotal] = (int)(~(u32)(bk & 0xFFFFFFFFull));
            }
            condTotal++;                         // uniform
            par ^= 1;
        }

        __syncthreads();   // pop LDS quiesced before next pass reset
        if (condTotal >= 1024 || ++passes > 128) break;   // safety
    }

    for (int i = tid; i < condTotal; i += 1024)
        condList[(size_t)s * CCAP + i] = ctrGi[i];
    if (tid == 0) condCount[s] = condTotal;
}

// Rank-sort each segment's pick list ascending, global sorted order,
// ncond cumulative counts as float32.
__global__ void finalize_kernel(const int* __restrict__ condList,
                                const int* __restrict__ condCount, int CCAP,
                                int* __restrict__ sorted, int* __restrict__ prefix,
                                float* __restrict__ ncond_out, int nseg, int rows) {
    __shared__ int lst[2048];
    __shared__ int pfx[9];
    int tid = threadIdx.x;
    if (tid == 0) {
        int acc = 0; pfx[0] = 0;
        for (int s2 = 0; s2 < nseg; s2++) { acc += condCount[s2]; pfx[s2 + 1] = acc; }
    }
    __syncthreads();
    if (tid <= nseg) { prefix[tid] = pfx[tid]; ncond_out[tid] = (float)pfx[tid]; }
    for (int s2 = 0; s2 < nseg; s2++) {
        int ns = condCount[s2]; if (ns > CCAP) ns = CCAP;
        for (int i = tid; i < ns; i += blockDim.x) lst[i] = condList[(size_t)s2 * CCAP + i];
        __syncthreads();
        for (int i = tid; i < ns; i += blockDim.x) {
            int v = lst[i]; int rank = 0;
            for (int j = 0; j < ns; j++) rank += (lst[j] < v);
            int pos = pfx[s2] + rank;
            if (pos < rows) sorted[pos] = v;
        }
        __syncthreads();
    }
}

__global__ void emit_kernel(const float* __restrict__ x, const int* __restrict__ sorted,
                            const int* __restrict__ prefix, float* __restrict__ out,
                            int rows, int nseg) {
    int e = blockIdx.x * blockDim.x + threadIdx.x;
    if (e >= rows * 17) return;
    int total = prefix[nseg];
    int j = e / 17, k = e - j * 17;
    float v = 0.f;
    if (j < total) v = x[(size_t)sorted[j] * 17 + k];
    out[e] = v;
}

extern "C" void kernel_launch(void* const* d_in, const int* in_sizes, int n_in,
                              void* d_out, int out_size, void* d_ws, size_t ws_size,
                              hipStream_t stream) {
    const float* x = (const float*)d_in[0];
    const int nseg = in_sizes[1] - 1;          // 4
    const int N = in_sizes[0] / 17;            // 1,000,000
    const int S = N / nseg;                    // 250,000
    const int rows = (out_size - (nseg + 1)) / 17;  // 1024 (MAX_COND)
    const int CCAP = 2048;

    const int bps = 1024 / nseg;               // blocks per segment (256)
    const int nBlocks = nseg * bps;            // 1024
    const int chunk = (S + bps - 1) / bps;     // 977 (< 1024 LDS staging cap)

    // workspace: [A float4][iA][condList][segCount][condCount][sorted][prefix]
    char* w = (char*)d_ws;
    size_t fixedBytes = (size_t)nseg * CCAP * 4 + (size_t)nseg * 4 * 2 +
                        (size_t)rows * 4 + (size_t)(nseg + 1) * 4 + 4096;
    size_t perCand = (size_t)nseg * (16 + 4);
    size_t avail = (ws_size > fixedBytes) ? (ws_size - fixedBytes) : 0;
    int CAP = (int)(avail / perCand);
    if (CAP > 65536) CAP = 65536;   // 64-bit alive-mask limit (64*1024)
    if (CAP < 1) CAP = 1;

    float4* A = (float4*)w;
    int* iA = (int*)(A + (size_t)nseg * CAP);
    int* condList  = iA + (size_t)nseg * CAP;
    int* segCount  = condList + (size_t)nseg * CCAP;
    int* condCount = segCount + nseg;
    int* sorted    = condCount + nseg;
    int* prefix    = sorted + rows;
    float* out = (float*)d_out;

    init_kernel<<<1, 64, 0, stream>>>(segCount, condCount, nseg);
    filter_kernel<<<nBlocks, 256, 0, stream>>>(x, S, chunk, bps, segCount, A, iA, CAP);
    greedy_kernel<<<nseg, 1024, 0, stream>>>(A, iA, segCount, CAP,
                                             condList, condCount, CCAP);
    finalize_kernel<<<1, 256, 0, stream>>>(condList, condCount, CCAP, sorted, prefix,
                                           out + (size_t)rows * 17, nseg, rows);
    emit_kernel<<<(rows * 17 + 255) / 256, 256, 0, stream>>>(x, sorted, prefix, out,
                                                             rows, nseg);
}

// Round 7
// 355.774 us; speedup vs baseline: 1.2171x; 1.2171x over previous
//
#include <hip/hip_runtime.h>
#include <stdint.h>

typedef unsigned long long u64;
typedef unsigned int u32;

// ---------------------------------------------------------------------------
// Constants: 17 feats/row, beta = col 9, cc = cols 14..16, T_B=0.85, T_D^2=0.09.
// Greedy condensation == scan candidates in descending (betaBits, ~idx) key
// order, accept iff not within T_D of any previously accepted center.
// R7: key-BAND decomposition replaces the multi-pass horizon machinery
// (R3/R4/R6 all mispredicted its pass-count dynamics). A candidate's fate
// depends only on higher-key picks, so: process band [0.995, inf) fully in
// LDS (~1250 entries), then band [0, 0.995) pruned vs all committed centers
// (~40 survivors). Structurally 2 sweeps + one pick-iteration per pick.
// ---------------------------------------------------------------------------

__global__ void init_kernel(int* segCount, int* condCount, int nseg) {
    int t = threadIdx.x;
    if (t < nseg) { segCount[t] = 0; condCount[t] = 0; }
}

// Single-pass filter: block-local LDS staging, ONE global atomic per block.
__launch_bounds__(256)
__global__ void filter_kernel(const float* __restrict__ x, int S, int chunk, int bps,
                              int* __restrict__ segCount,
                              float4* __restrict__ A, int* __restrict__ iA, int CAP) {
    __shared__ float4 stg[1024];
    __shared__ int sgi[1024];
    __shared__ int s_cnt, s_base;
    int b = blockIdx.x;
    int s = b / bps, c = b % bps;
    int start = s * S + c * chunk;
    int end = min(start + chunk, s * S + S);
    if (threadIdx.x == 0) s_cnt = 0;
    __syncthreads();
    for (int i = start + threadIdx.x; i < end; i += 256) {
        float beta = x[(size_t)i * 17 + 9];
        if (beta >= 0.85f) {
            int p = atomicAdd(&s_cnt, 1);
            if (p < 1024) {
                stg[p] = make_float4(x[(size_t)i * 17 + 14], x[(size_t)i * 17 + 15],
                                     x[(size_t)i * 17 + 16], beta);
                sgi[p] = i;
            }
        }
    }
    __syncthreads();
    if (threadIdx.x == 0) s_base = atomicAdd(&segCount[s], min(s_cnt, 1024));
    __syncthreads();
    int cnt = min(s_cnt, 1024);
    for (int k = threadIdx.x; k < cnt; k += 256) {
        int pos = s_base + k;
        if (pos < CAP) {
            A[(size_t)s * CAP + pos] = stg[k];
            iA[(size_t)s * CAP + pos] = sgi[k];
        }
    }
}

#define DSQ(ax,ay,az,bx,by,bz) \
    __fadd_rn(__fadd_rn(__fmul_rn(__fsub_rn(ax,bx),__fsub_rn(ax,bx)), \
                        __fmul_rn(__fsub_rn(ay,by),__fsub_rn(ay,by))), \
              __fmul_rn(__fsub_rn(az,bz),__fsub_rn(az,bz)))

// One block (1024 thr) per segment.
__launch_bounds__(1024)
__global__ void greedy_kernel(const float4* __restrict__ A, const int* __restrict__ iA,
                              const int* __restrict__ candCount, int CAP,
                              int* __restrict__ condList, int* __restrict__ condCount,
                              int CCAP) {
    const int s = blockIdx.x;
    const int tid = threadIdx.x;
    const int lane = tid & 63;
    const int wid = tid >> 6;

    __shared__ u64 bandKey[2048];
    __shared__ float4 band[2048];
    __shared__ int bandGi[2048];
    __shared__ u64 wkey[2][16];
    __shared__ int widx[2][16];
    __shared__ float4 ctr[1024];
    __shared__ int ctrGi[1024];
    __shared__ int s_cnt;

    const float4* cand = A + (size_t)s * CAP;
    const int* gia = iA + (size_t)s * CAP;
    int n = candCount[s]; if (n > CAP) n = CAP;

    int condTotal = 0;
    int par = 0;
    float hiB = 2.0f, loB = 0.995f;

    while (true) {
        // ---- stage band [loB, hiB) pruned vs committed centers; retry on
        // overflow with a narrower band (exactness-preserving bisection) ----
        while (true) {
            if (tid == 0) s_cnt = 0;
            bandKey[tid] = 0;
            bandKey[tid + 1024] = 0;
            __syncthreads();
            for (int j = tid; j < n; j += 1024) {
                float4 c = cand[j];
                if (c.w >= loB && c.w < hiB) {
                    bool live = true;
                    for (int m = 0; m < condTotal; ++m) {
                        float4 q = ctr[m];   // uniform m -> LDS broadcast
                        if (DSQ(c.x, c.y, c.z, q.x, q.y, q.z) < 0.09f) { live = false; break; }
                    }
                    if (live) {
                        int g = gia[j];
                        int p = atomicAdd(&s_cnt, 1);
                        if (p < 2048) {
                            bandKey[p] = ((u64)__float_as_uint(c.w) << 32) | (u64)(~(u32)g);
                            band[p] = c;
                            bandGi[p] = g;
                        }
                    }
                }
            }
            __syncthreads();
            if (s_cnt <= 2048) break;
            loB = 0.5f * (fmaxf(loB, 0.85f) + fminf(hiB, 1.0f));
            __syncthreads();
        }

        // ---- register-cache own 2 entries ----
        u64 ka = bandKey[tid];
        u64 kb = bandKey[tid + 1024];
        float4 ca = band[tid];
        float4 cb = band[tid + 1024];

        // ---- pick loop: one barrier per committed pick ----
        while (condTotal < 1024) {
            u64 mk = ka; int mi = tid;
            if (kb > mk) { mk = kb; mi = tid + 1024; }
            for (int off = 32; off > 0; off >>= 1) {
                u64 ok = __shfl_xor(mk, off);
                int oi = __shfl_xor(mi, off);
                if (ok > mk) { mk = ok; mi = oi; }
            }
            if (lane == 0) { wkey[par][wid] = mk; widx[par][wid] = mi; }
            __syncthreads();
            u64 bk = 0; int bi = 0;
            #pragma unroll
            for (int w = 0; w < 16; ++w) {
                u64 kk = wkey[par][w];
                if (kk > bk) { bk = kk; bi = widx[par][w]; }
            }
            if (bk == 0) break;                 // band exhausted (uniform)
            float4 cc = band[bi];               // uniform -> LDS broadcast
            // kill own covered entries (winner kills itself at dist 0)
            if (ka && DSQ(ca.x, ca.y, ca.z, cc.x, cc.y, cc.z) < 0.09f) ka = 0;
            if (kb && DSQ(cb.x, cb.y, cb.z, cc.x, cc.y, cc.z) < 0.09f) kb = 0;
            if (tid == 0) {
                ctr[condTotal] = cc;
                ctrGi[condTotal] = bandGi[bi];
            }
            condTotal++;                        // uniform
            par ^= 1;
        }
        __syncthreads();   // picks visible before next band stage / writeout

        if (loB < 0.8501f) break;   // floor covered: all bands done
        hiB = loB; loB = 0.0f;      // rest of the key range in one band
    }

    for (int i = tid; i < condTotal; i += 1024)
        condList[(size_t)s * CCAP + i] = ctrGi[i];
    if (tid == 0) condCount[s] = condTotal;
}

// Rank-sort each segment's pick list ascending, global sorted order,
// ncond cumulative counts as float32.
__global__ void finalize_kernel(const int* __restrict__ condList,
                                const int* __restrict__ condCount, int CCAP,
                                int* __restrict__ sorted, int* __restrict__ prefix,
                                float* __restrict__ ncond_out, int nseg, int rows) {
    __shared__ int lst[2048];
    __shared__ int pfx[9];
    int tid = threadIdx.x;
    if (tid == 0) {
        int acc = 0; pfx[0] = 0;
        for (int s2 = 0; s2 < nseg; s2++) { acc += condCount[s2]; pfx[s2 + 1] = acc; }
    }
    __syncthreads();
    if (tid <= nseg) { prefix[tid] = pfx[tid]; ncond_out[tid] = (float)pfx[tid]; }
    for (int s2 = 0; s2 < nseg; s2++) {
        int ns = condCount[s2]; if (ns > CCAP) ns = CCAP;
        for (int i = tid; i < ns; i += blockDim.x) lst[i] = condList[(size_t)s2 * CCAP + i];
        __syncthreads();
        for (int i = tid; i < ns; i += blockDim.x) {
            int v = lst[i]; int rank = 0;
            for (int j = 0; j < ns; j++) rank += (lst[j] < v);
            int pos = pfx[s2] + rank;
            if (pos < rows) sorted[pos] = v;
        }
        __syncthreads();
    }
}

__global__ void emit_kernel(const float* __restrict__ x, const int* __restrict__ sorted,
                            const int* __restrict__ prefix, float* __restrict__ out,
                            int rows, int nseg) {
    int e = blockIdx.x * blockDim.x + threadIdx.x;
    if (e >= rows * 17) return;
    int total = prefix[nseg];
    int j = e / 17, k = e - j * 17;
    float v = 0.f;
    if (j < total) v = x[(size_t)sorted[j] * 17 + k];
    out[e] = v;
}

extern "C" void kernel_launch(void* const* d_in, const int* in_sizes, int n_in,
                              void* d_out, int out_size, void* d_ws, size_t ws_size,
                              hipStream_t stream) {
    const float* x = (const float*)d_in[0];
    const int nseg = in_sizes[1] - 1;          // 4
    const int N = in_sizes[0] / 17;            // 1,000,000
    const int S = N / nseg;                    // 250,000
    const int rows = (out_size - (nseg + 1)) / 17;  // 1024 (MAX_COND)
    const int CCAP = 2048;

    const int bps = 1024 / nseg;               // blocks per segment (256)
    const int nBlocks = nseg * bps;            // 1024
    const int chunk = (S + bps - 1) / bps;     // 977 (< 1024 LDS staging cap)

    // workspace: [A float4][iA][condList][segCount][condCount][sorted][prefix]
    char* w = (char*)d_ws;
    size_t fixedBytes = (size_t)nseg * CCAP * 4 + (size_t)nseg * 4 * 2 +
                        (size_t)rows * 4 + (size_t)(nseg + 1) * 4 + 4096;
    size_t perCand = (size_t)nseg * (16 + 4);
    size_t avail = (ws_size > fixedBytes) ? (ws_size - fixedBytes) : 0;
    int CAP = (int)(avail / perCand);
    if (CAP > 65536) CAP = 65536;
    if (CAP < 1) CAP = 1;

    float4* A = (float4*)w;
    int* iA = (int*)(A + (size_t)nseg * CAP);
    int* condList  = iA + (size_t)nseg * CAP;
    int* segCount  = condList + (size_t)nseg * CCAP;
    int* condCount = segCount + nseg;
    int* sorted    = condCount + nseg;
    int* prefix    = sorted + rows;
    float* out = (float*)d_out;

    init_kernel<<<1, 64, 0, stream>>>(segCount, condCount, nseg);
    filter_kernel<<<nBlocks, 256, 0, stream>>>(x, S, chunk, bps, segCount, A, iA, CAP);
    greedy_kernel<<<nseg, 1024, 0, stream>>>(A, iA, segCount, CAP,
                                             condList, condCount, CCAP);
    finalize_kernel<<<1, 256, 0, stream>>>(condList, condCount, CCAP, sorted, prefix,
                                           out + (size_t)rows * 17, nseg, rows);
    emit_kernel<<<(rows * 17 + 255) / 256, 256, 0, stream>>>(x, sorted, prefix, out,
                                                             rows, nseg);
}